// Round 2
// baseline (984.979 us; speedup 1.0000x reference)
//
#include <hip/hip_runtime.h>
#include <hip/hip_bf16.h>

#define D 32

typedef const float* fp;

// h[n][o] = x[n][0]*W_emb[0][o] + x[n][1]*W_emb[1][o] + b_emb[o]
__global__ void k_embed(fp x, fp W_emb, fp b_emb, float* __restrict__ h, int N) {
    int t = blockIdx.x * 256 + threadIdx.x;
    if (t >= N * D) return;
    int n = t >> 5, o = t & 31;
    h[t] = x[n * 2] * W_emb[o] + x[n * 2 + 1] * W_emb[D + o] + b_emb[o];
}

// per edge: he = relu((hd-hs)@W_theta + hs@W_phi + bth + bph); g = relu(he@W1 + b1)
__global__ void k_edge(const float* __restrict__ h, const int* __restrict__ src,
                       const int* __restrict__ dst, fp Wth, fp bth, fp Wph, fp bph,
                       fp W1, fp b1, float* __restrict__ g, int E) {
    __shared__ float sWth[D * D], sWph[D * D], sW1[D * 64], sbt[D], sb1[64];
    __shared__ float she[4][D], shs[4][D], shd[4][D];
    for (int i = threadIdx.x; i < D * D; i += 256) { sWth[i] = Wth[i]; sWph[i] = Wph[i]; }
    for (int i = threadIdx.x; i < D * 64; i += 256) sW1[i] = W1[i];
    if (threadIdx.x < D) sbt[threadIdx.x] = bth[threadIdx.x] + bph[threadIdx.x];
    if (threadIdx.x >= 64 && threadIdx.x < 128) sb1[threadIdx.x - 64] = b1[threadIdx.x - 64];
    __syncthreads();
    int sub = threadIdx.x >> 6, lane = threadIdx.x & 63;
    for (int e0 = blockIdx.x * 4; e0 < E; e0 += gridDim.x * 4) {
        int e = e0 + sub;
        bool valid = (e < E);
        if (valid && lane < D) {
            int s = src[e], d2 = dst[e];
            shs[sub][lane] = h[s * D + lane];
            shd[sub][lane] = h[d2 * D + lane];
        }
        __syncthreads();
        if (valid && lane < D) {
            float acc = sbt[lane];
            #pragma unroll
            for (int i = 0; i < D; ++i) {
                float hs = shs[sub][i];
                acc += (shd[sub][i] - hs) * sWth[i * D + lane] + hs * sWph[i * D + lane];
            }
            she[sub][lane] = fmaxf(acc, 0.f);
        }
        __syncthreads();
        if (valid) {
            float acc = sb1[lane];
            #pragma unroll
            for (int o = 0; o < D; ++o) acc += she[sub][o] * sW1[o * 64 + lane];
            g[(long)e * 64 + lane] = fmaxf(acc, 0.f);
        }
        __syncthreads();
    }
}

// M[n][k*32+o] = sum_i h[n][i] * W2[k*1024 + i*32 + o]   (k<64, o<32)
__global__ void k_M(const float* __restrict__ h, fp W2, float* __restrict__ M) {
    __shared__ float sh[D];
    int n = blockIdx.x >> 3;
    int ko = ((blockIdx.x & 7) << 8) + threadIdx.x;  // 0..2047
    if (threadIdx.x < D) sh[threadIdx.x] = h[n * D + threadIdx.x];
    __syncthreads();
    int k = ko >> 5, o = ko & 31;
    const float* w = W2 + k * 1024 + o;
    float acc = 0.f;
    #pragma unroll
    for (int i = 0; i < D; ++i) acc += sh[i] * w[i * 32];
    M[(long)n * 2048 + ko] = acc;
}

// B[n][o] = sum_i h[n][i] * b2[i*32+o]
__global__ void k_B(const float* __restrict__ h, fp b2, float* __restrict__ B, int N) {
    int t = blockIdx.x * 256 + threadIdx.x;
    if (t >= N * D) return;
    int n = t >> 5, o = t & 31;
    float acc = 0.f;
    #pragma unroll
    for (int i = 0; i < D; ++i) acc += h[n * D + i] * b2[i * 32 + o];
    B[t] = acc;
}

// msg_e[o] = B[src][o] + sum_k g[e][k] * M[src][k*32+o];  a[dst][o] += msg
__global__ void k_msg(const float* __restrict__ M, const float* __restrict__ B,
                      const float* __restrict__ g, const int* __restrict__ src,
                      const int* __restrict__ dst, float* __restrict__ a, int E) {
    __shared__ float sg[8][64];
    int e0 = blockIdx.x * 8;
    for (int i = threadIdx.x; i < 512; i += 256) {
        int e = e0 + (i >> 6);
        if (e < E) sg[i >> 6][i & 63] = g[(long)e * 64 + (i & 63)];
    }
    __syncthreads();
    int sub = threadIdx.x >> 5, o = threadIdx.x & 31;
    int e = e0 + sub;
    if (e >= E) return;
    int s = src[e], d2 = dst[e];
    const float* m = M + (long)s * 2048 + o;
    float acc = B[s * D + o];
    #pragma unroll
    for (int k = 0; k < 64; ++k) acc += sg[sub][k] * m[k * 32];
    atomicAdd(a + d2 * D + o, acc);
}

// torch GRUCell
__global__ void k_gru(const float* __restrict__ a, const float* __restrict__ h,
                      fp W_ih, fp b_ih, fp W_hh, fp b_hh,
                      float* __restrict__ hout, int N) {
    __shared__ float sa[8][D], sh[8][D];
    int n0 = blockIdx.x * 8;
    for (int i = threadIdx.x; i < 8 * D; i += 256) {
        int n = n0 + (i >> 5);
        if (n < N) { sa[i >> 5][i & 31] = a[n * D + (i & 31)]; sh[i >> 5][i & 31] = h[n * D + (i & 31)]; }
    }
    __syncthreads();
    int sub = threadIdx.x >> 5, o = threadIdx.x & 31;
    int n = n0 + sub;
    if (n >= N) return;
    float ir = b_ih[o], iz = b_ih[D + o], in_ = b_ih[2 * D + o];
    float hr = b_hh[o], hz = b_hh[D + o], hn = b_hh[2 * D + o];
    #pragma unroll
    for (int i = 0; i < D; ++i) {
        float av = sa[sub][i], hv = sh[sub][i];
        ir += av * W_ih[i * 96 + o];
        iz += av * W_ih[i * 96 + D + o];
        in_ += av * W_ih[i * 96 + 2 * D + o];
        hr += hv * W_hh[i * 96 + o];
        hz += hv * W_hh[i * 96 + D + o];
        hn += hv * W_hh[i * 96 + 2 * D + o];
    }
    float r = 1.f / (1.f + __expf(-(ir + hr)));
    float z = 1.f / (1.f + __expf(-(iz + hz)));
    float nn = tanhf(in_ + r * hn);
    hout[n * D + o] = (1.f - z) * nn + z * sh[sub][o];
}

extern "C" void kernel_launch(void* const* d_in, const int* in_sizes, int n_in,
                              void* d_out, int out_size, void* d_ws, size_t ws_size,
                              hipStream_t stream) {
    fp x      = (fp)d_in[0];
    const int* src = (const int*)d_in[1];
    const int* dst = (const int*)d_in[2];
    fp W_emb  = (fp)d_in[3];
    fp b_emb  = (fp)d_in[4];
    fp W_th   = (fp)d_in[5];
    fp b_th   = (fp)d_in[6];
    fp W_ph   = (fp)d_in[7];
    fp b_ph   = (fp)d_in[8];
    fp W1     = (fp)d_in[9];
    fp b1     = (fp)d_in[10];
    fp W2     = (fp)d_in[11];
    fp b2     = (fp)d_in[12];
    fp W_ih   = (fp)d_in[13];
    fp b_ih   = (fp)d_in[14];
    fp W_hh   = (fp)d_in[15];
    fp b_hh   = (fp)d_in[16];

    const int N = in_sizes[0] / 2;   // x is [N,2]
    const int E = in_sizes[1];

    float* hA = (float*)d_ws;              // N*32
    float* hB = hA + (size_t)N * D;        // N*32
    float* g  = hB + (size_t)N * D;        // E*64
    float* M  = g + (size_t)E * 64;        // N*2048
    float* B  = M + (size_t)N * 2048;      // N*32
    float* a  = B + (size_t)N * D;         // N*32

    int ndThreads = N * D;
    int ndBlocks = (ndThreads + 255) / 256;

    k_embed<<<ndBlocks, 256, 0, stream>>>(x, W_emb, b_emb, hA, N);
    k_edge<<<2048, 256, 0, stream>>>(hA, src, dst, W_th, b_th, W_ph, b_ph, W1, b1, g, E);

    float* hc = hA;
    float* hn_ = hB;
    for (int step = 0; step < 3; ++step) {
        k_M<<<N * 8, 256, 0, stream>>>(hc, W2, M);
        k_B<<<ndBlocks, 256, 0, stream>>>(hc, b2, B, N);
        hipMemsetAsync(a, 0, (size_t)N * D * sizeof(float), stream);
        k_msg<<<(E + 7) / 8, 256, 0, stream>>>(M, B, g, src, dst, a, E);
        k_gru<<<(N + 7) / 8, 256, 0, stream>>>(a, hc, W_ih, b_ih, W_hh, b_hh, hn_, N);
        float* t = hc; hc = hn_; hn_ = t;
    }
    // output is float32 per reference
    hipMemcpyAsync(d_out, hc, (size_t)N * D * sizeof(float), hipMemcpyDeviceToDevice, stream);
}

// Round 3
// 410.265 us; speedup vs baseline: 2.4008x; 2.4008x over previous
//
#include <hip/hip_runtime.h>
#include <hip/hip_bf16.h>

#define D 32

typedef const float* fp;
typedef unsigned short u16;
typedef unsigned int u32;

__device__ __forceinline__ float b2f(u32 lo16) { return __uint_as_float(lo16 << 16); }
__device__ __forceinline__ u16 f2b(float f) {
    u32 x = __float_as_uint(f);
    return (u16)((x + 0x7fffu + ((x >> 16) & 1u)) >> 16);   // RNE
}

// h[n][o] = x[n][0]*W_emb[0][o] + x[n][1]*W_emb[1][o] + b_emb[o]
__global__ void k_embed(fp x, fp W_emb, fp b_emb, float* __restrict__ h, int N) {
    int t = blockIdx.x * 256 + threadIdx.x;
    if (t >= N * D) return;
    int n = t >> 5, o = t & 31;
    h[t] = x[n * 2] * W_emb[o] + x[n * 2 + 1] * W_emb[D + o] + b_emb[o];
}

__global__ void k_count(const int* __restrict__ src, int* __restrict__ cnt, int E) {
    int e = blockIdx.x * 256 + threadIdx.x;
    if (e < E) atomicAdd(&cnt[src[e]], 1);
}

// single block, 1024 threads: exclusive prefix sum cnt[0..N) -> roff[0..N]
__global__ void k_scan(const int* __restrict__ cnt, int* __restrict__ roff, int N) {
    __shared__ int part[1024];
    int t = threadIdx.x;
    int per = (N + 1023) / 1024;
    int begin = t * per, end = min(begin + per, N);
    int s = 0;
    for (int i = begin; i < end; ++i) s += cnt[i];
    part[t] = s;
    __syncthreads();
    for (int off = 1; off < 1024; off <<= 1) {
        int v = (t >= off) ? part[t - off] : 0;
        __syncthreads();
        part[t] += v;
        __syncthreads();
    }
    int pre = (t == 0) ? 0 : part[t - 1];
    for (int i = begin; i < end; ++i) { roff[i] = pre; pre += cnt[i]; }
    if (t == 0) roff[N] = part[1023];
}

__global__ void k_scatter(const int* __restrict__ src, const int* __restrict__ dst,
                          const int* __restrict__ roff, int* __restrict__ cursor,
                          int* __restrict__ pos_of, int* __restrict__ sdst, int E) {
    int e = blockIdx.x * 256 + threadIdx.x;
    if (e >= E) return;
    int s = src[e];
    int p = roff[s] + atomicAdd(&cursor[s], 1);
    pos_of[e] = p;
    sdst[p] = dst[e];
}

// thread-per-edge: he = relu(hd@Wth + hs@(Wph-Wth) + bt); g_row(pos_of[e]) = relu(he@W1+b1) in bf16
__global__ void k_edge(const float* __restrict__ h, const int* __restrict__ src,
                       const int* __restrict__ dst, const int* __restrict__ pos_of,
                       fp Wth, fp bth, fp Wph, fp bph, fp W1, fp b1,
                       u16* __restrict__ g, int E) {
    __shared__ float sWd[D * D], sWs[D * D], sW1[D * 64], sbt[D], sb1[64];
    for (int i = threadIdx.x; i < D * D; i += 256) { float wt = Wth[i]; sWd[i] = wt; sWs[i] = Wph[i] - wt; }
    for (int i = threadIdx.x; i < D * 64; i += 256) sW1[i] = W1[i];
    if (threadIdx.x < D) sbt[threadIdx.x] = bth[threadIdx.x] + bph[threadIdx.x];
    if (threadIdx.x >= 64 && threadIdx.x < 128) sb1[threadIdx.x - 64] = b1[threadIdx.x - 64];
    __syncthreads();
    int e = blockIdx.x * 256 + threadIdx.x;
    if (e >= E) return;
    int s = src[e], d2 = dst[e];
    float hs[D], hd[D], he[D];
    const float4* ps = (const float4*)(h + (size_t)s * D);
    const float4* pd = (const float4*)(h + (size_t)d2 * D);
    #pragma unroll
    for (int i = 0; i < D / 4; ++i) {
        float4 v = ps[i]; hs[4*i] = v.x; hs[4*i+1] = v.y; hs[4*i+2] = v.z; hs[4*i+3] = v.w;
        float4 w = pd[i]; hd[4*i] = w.x; hd[4*i+1] = w.y; hd[4*i+2] = w.z; hd[4*i+3] = w.w;
    }
    #pragma unroll
    for (int o = 0; o < D; ++o) he[o] = sbt[o];
    #pragma unroll
    for (int i = 0; i < D; ++i) {
        float a_ = hd[i], b_ = hs[i];
        #pragma unroll
        for (int o = 0; o < D; ++o) he[o] += a_ * sWd[i * D + o] + b_ * sWs[i * D + o];
    }
    #pragma unroll
    for (int o = 0; o < D; ++o) he[o] = fmaxf(he[o], 0.f);

    u32* grow = (u32*)g + (size_t)pos_of[e] * 32;
    for (int k0 = 0; k0 < 64; k0 += 8) {
        u32 parts[4];
        #pragma unroll
        for (int j = 0; j < 4; ++j) {
            int k = k0 + 2 * j;
            float a0 = sb1[k], a1 = sb1[k + 1];
            #pragma unroll
            for (int o = 0; o < D; ++o) {
                float hv = he[o];
                a0 += hv * sW1[o * 64 + k];
                a1 += hv * sW1[o * 64 + k + 1];
            }
            parts[j] = (u32)f2b(fmaxf(a0, 0.f)) | ((u32)f2b(fmaxf(a1, 0.f)) << 16);
        }
        uint4 pk = make_uint4(parts[0], parts[1], parts[2], parts[3]);
        *(uint4*)(grow + k0 / 2) = pk;
    }
}

// M[n][ko] (bf16) = sum_i h[n][i] * W2[k*1024 + i*32 + o], ko = k*32+o
// grid: ceil(N/128) x 8 ko-slices of 256; thread owns one ko (W2 column in 32 VGPRs)
__global__ void k_M(const float* __restrict__ h, fp W2, u16* __restrict__ M, int N) {
    __shared__ float sh[128 * D];
    int n0 = (blockIdx.x >> 3) * 128;
    int ko = ((blockIdx.x & 7) << 8) + threadIdx.x;
    int k = ko >> 5, o = ko & 31;
    float w[D];
    const float* wp = W2 + (size_t)k * 1024 + o;
    #pragma unroll
    for (int i = 0; i < D; ++i) w[i] = wp[i * 32];
    int nn = min(128, N - n0);
    for (int i = threadIdx.x; i < nn * (D / 4); i += 256) {
        ((float4*)sh)[i] = ((const float4*)(h + (size_t)n0 * D))[i];
    }
    __syncthreads();
    for (int n = 0; n < nn; ++n) {
        const float4* hv = (const float4*)(sh + n * D);
        float acc = 0.f;
        #pragma unroll
        for (int i4 = 0; i4 < D / 4; ++i4) {
            float4 v = hv[i4];
            acc += v.x * w[4*i4] + v.y * w[4*i4+1] + v.z * w[4*i4+2] + v.w * w[4*i4+3];
        }
        M[(size_t)(n0 + n) * 2048 + ko] = f2b(acc);
    }
}

// B[n][o] = sum_i h[n][i] * b2[i*32+o]
__global__ void k_B(const float* __restrict__ h, fp b2, float* __restrict__ B, int N) {
    __shared__ float sb2[1024];
    for (int i = threadIdx.x; i < 1024; i += 256) sb2[i] = b2[i];
    __syncthreads();
    int t = blockIdx.x * 256 + threadIdx.x;
    if (t >= N * D) return;
    int n = t >> 5, o = t & 31;
    float acc = 0.f;
    #pragma unroll
    for (int i = 0; i < D; ++i) acc += h[n * D + i] * sb2[i * 32 + o];
    B[t] = acc;
}

// block per src node s: load M[s] row to LDS, apply to all out-edges, atomicAdd to a[dst]
__global__ void k_msg(const u16* __restrict__ M, const float* __restrict__ B,
                      const u16* __restrict__ g, const int* __restrict__ roff,
                      const int* __restrict__ sdst, float* __restrict__ a) {
    int s = blockIdx.x;
    int beg = roff[s], end = roff[s + 1];
    if (beg >= end) return;
    __shared__ float sM[2048];
    __shared__ float sB[D];
    __shared__ float sg[8][64];
    {
        uint4 pk = ((const uint4*)(M + (size_t)s * 2048))[threadIdx.x];
        int b0 = threadIdx.x * 8;
        sM[b0 + 0] = b2f(pk.x & 0xffff); sM[b0 + 1] = b2f(pk.x >> 16);
        sM[b0 + 2] = b2f(pk.y & 0xffff); sM[b0 + 3] = b2f(pk.y >> 16);
        sM[b0 + 4] = b2f(pk.z & 0xffff); sM[b0 + 5] = b2f(pk.z >> 16);
        sM[b0 + 6] = b2f(pk.w & 0xffff); sM[b0 + 7] = b2f(pk.w >> 16);
    }
    if (threadIdx.x < D) sB[threadIdx.x] = B[(size_t)s * D + threadIdx.x];
    __syncthreads();
    int sub = threadIdx.x >> 5, o = threadIdx.x & 31;
    for (int eb = beg; eb < end; eb += 8) {
        int nE = min(8, end - eb);
        if (sub < nE) {
            u32 pk = ((const u32*)g)[(size_t)(eb + sub) * 32 + o];
            sg[sub][2 * o] = b2f(pk & 0xffff);
            sg[sub][2 * o + 1] = b2f(pk >> 16);
        }
        __syncthreads();
        if (sub < nE) {
            float acc = sB[o];
            #pragma unroll
            for (int kk = 0; kk < 64; ++kk) acc += sg[sub][kk] * sM[kk * 32 + o];
            atomicAdd(&a[(size_t)sdst[eb + sub] * D + o], acc);
        }
        __syncthreads();
    }
}

// torch GRUCell; zeroes a in place for the next step
__global__ void k_gru(float* __restrict__ a, const float* __restrict__ h,
                      fp W_ih, fp b_ih, fp W_hh, fp b_hh,
                      float* __restrict__ hout, int N) {
    __shared__ float sa[8][D], sh[8][D];
    int n0 = blockIdx.x * 8;
    for (int i = threadIdx.x; i < 8 * D; i += 256) {
        int n = n0 + (i >> 5);
        if (n < N) {
            size_t idx = (size_t)n * D + (i & 31);
            sa[i >> 5][i & 31] = a[idx];
            sh[i >> 5][i & 31] = h[idx];
            a[idx] = 0.f;
        }
    }
    __syncthreads();
    int sub = threadIdx.x >> 5, o = threadIdx.x & 31;
    int n = n0 + sub;
    if (n >= N) return;
    float ir = b_ih[o], iz = b_ih[D + o], in_ = b_ih[2 * D + o];
    float hr = b_hh[o], hz = b_hh[D + o], hn = b_hh[2 * D + o];
    #pragma unroll
    for (int i = 0; i < D; ++i) {
        float av = sa[sub][i], hv = sh[sub][i];
        ir += av * W_ih[i * 96 + o];
        iz += av * W_ih[i * 96 + D + o];
        in_ += av * W_ih[i * 96 + 2 * D + o];
        hr += hv * W_hh[i * 96 + o];
        hz += hv * W_hh[i * 96 + D + o];
        hn += hv * W_hh[i * 96 + 2 * D + o];
    }
    float r = 1.f / (1.f + __expf(-(ir + hr)));
    float z = 1.f / (1.f + __expf(-(iz + hz)));
    float nn = tanhf(in_ + r * hn);
    hout[(size_t)n * D + o] = (1.f - z) * nn + z * sh[sub][o];
}

extern "C" void kernel_launch(void* const* d_in, const int* in_sizes, int n_in,
                              void* d_out, int out_size, void* d_ws, size_t ws_size,
                              hipStream_t stream) {
    fp x      = (fp)d_in[0];
    const int* src = (const int*)d_in[1];
    const int* dst = (const int*)d_in[2];
    fp W_emb  = (fp)d_in[3];
    fp b_emb  = (fp)d_in[4];
    fp W_th   = (fp)d_in[5];
    fp b_th   = (fp)d_in[6];
    fp W_ph   = (fp)d_in[7];
    fp b_ph   = (fp)d_in[8];
    fp W1     = (fp)d_in[9];
    fp b1     = (fp)d_in[10];
    fp W2     = (fp)d_in[11];
    fp b2     = (fp)d_in[12];
    fp W_ih   = (fp)d_in[13];
    fp b_ih   = (fp)d_in[14];
    fp W_hh   = (fp)d_in[15];
    fp b_hh   = (fp)d_in[16];

    const int N = in_sizes[0] / 2;   // x is [N,2]
    const int E = in_sizes[1];

    // workspace layout (4-byte units, all sub-arrays 16B-aligned by construction)
    float* a      = (float*)d_ws;                       // N*D f32
    int*   cnt    = (int*)(a + (size_t)N * D);          // N+1 (+pad)
    int*   cursor = cnt + (N + 4 - (N % 4));            // N  (cnt region padded to 4)
    int*   roff   = cursor + N;                         // N+1
    int*   pos_of = roff + (N + 4 - (N % 4));           // E
    int*   sdst   = pos_of + E;                         // E
    float* hA     = (float*)(sdst + E);                 // N*D
    float* hB     = hA + (size_t)N * D;                 // N*D
    u16*   g      = (u16*)(hB + (size_t)N * D);         // E*64 bf16
    u16*   M      = g + (size_t)E * 64;                 // N*2048 bf16
    float* B      = (float*)(M + (size_t)N * 2048);     // N*D

    // zero a + cnt + cursor in one memset (they are contiguous)
    size_t zbytes = (char*)(cursor + N) - (char*)a;
    hipMemsetAsync(a, 0, zbytes, stream);

    int ndBlocks = (N * D + 255) / 256;
    int eBlocks  = (E + 255) / 256;

    k_embed<<<ndBlocks, 256, 0, stream>>>(x, W_emb, b_emb, hA, N);
    k_count<<<eBlocks, 256, 0, stream>>>(src, cnt, E);
    k_scan<<<1, 1024, 0, stream>>>(cnt, roff, N);
    k_scatter<<<eBlocks, 256, 0, stream>>>(src, dst, roff, cursor, pos_of, sdst, E);
    k_edge<<<eBlocks, 256, 0, stream>>>(hA, src, dst, pos_of, W_th, b_th, W_ph, b_ph, W1, b1, g, E);

    int mBlocks = ((N + 127) / 128) * 8;
    float* hc = hA;
    float* hn_ = hB;
    for (int step = 0; step < 3; ++step) {
        k_M<<<mBlocks, 256, 0, stream>>>(hc, W2, M, N);
        k_B<<<ndBlocks, 256, 0, stream>>>(hc, b2, B, N);
        k_msg<<<N, 256, 0, stream>>>(M, B, g, roff, sdst, a);
        float* dstbuf = (step == 2) ? (float*)d_out : hn_;
        k_gru<<<(N + 7) / 8, 256, 0, stream>>>(a, hc, W_ih, b_ih, W_hh, b_hh, dstbuf, N);
        float* t = hc; hc = hn_; hn_ = t;
    }
}

// Round 4
// 381.635 us; speedup vs baseline: 2.5809x; 1.0750x over previous
//
#include <hip/hip_runtime.h>
#include <hip/hip_bf16.h>

#define D 32

typedef const float* fp;
typedef unsigned short u16;
typedef unsigned int u32;

__device__ __forceinline__ float b2f(u32 lo16) { return __uint_as_float(lo16 << 16); }
__device__ __forceinline__ u16 f2b(float f) {
    u32 x = __float_as_uint(f);
    return (u16)((x + 0x7fffu + ((x >> 16) & 1u)) >> 16);   // RNE
}

// h[n][o] = x[n][0]*W_emb[0][o] + x[n][1]*W_emb[1][o] + b_emb[o]
__global__ void k_embed(fp x, fp W_emb, fp b_emb, float* __restrict__ h, int N) {
    int t = blockIdx.x * 256 + threadIdx.x;
    if (t >= N * D) return;
    int n = t >> 5, o = t & 31;
    h[t] = x[n * 2] * W_emb[o] + x[n * 2 + 1] * W_emb[D + o] + b_emb[o];
}

__global__ void k_count(const int* __restrict__ src, int* __restrict__ cnt, int E) {
    int e = blockIdx.x * 256 + threadIdx.x;
    if (e < E) atomicAdd(&cnt[src[e]], 1);
}

// single block, 1024 threads: exclusive prefix sum cnt[0..N) -> roff[0..N]
__global__ void k_scan(const int* __restrict__ cnt, int* __restrict__ roff, int N) {
    __shared__ int part[1024];
    int t = threadIdx.x;
    int per = (N + 1023) / 1024;
    int begin = t * per, end = min(begin + per, N);
    int s = 0;
    for (int i = begin; i < end; ++i) s += cnt[i];
    part[t] = s;
    __syncthreads();
    for (int off = 1; off < 1024; off <<= 1) {
        int v = (t >= off) ? part[t - off] : 0;
        __syncthreads();
        part[t] += v;
        __syncthreads();
    }
    int pre = (t == 0) ? 0 : part[t - 1];
    for (int i = begin; i < end; ++i) { roff[i] = pre; pre += cnt[i]; }
    if (t == 0) roff[N] = part[1023];
}

__global__ void k_scatter(const int* __restrict__ src, const int* __restrict__ dst,
                          const int* __restrict__ roff, int* __restrict__ cursor,
                          int* __restrict__ ssrc, int* __restrict__ sdst, int E) {
    int e = blockIdx.x * 256 + threadIdx.x;
    if (e >= E) return;
    int s = src[e];
    int p = roff[s] + atomicAdd(&cursor[s], 1);
    ssrc[p] = s;
    sdst[p] = dst[e];
}

// sorted-domain, thread-per-edge: he = relu(hd@Wth + hs@(Wph-Wth) + bt); g[p] = relu(he@W1+b1) bf16
__global__ __launch_bounds__(256, 4)
void k_edge(const float* __restrict__ h, const int* __restrict__ ssrc,
            const int* __restrict__ sdst,
            fp Wth, fp bth, fp Wph, fp bph, fp W1, fp b1,
            u16* __restrict__ g, int E) {
    __shared__ float sWd[D * D], sWs[D * D], sW1[D * 64], sbt[D], sb1[64];
    for (int i = threadIdx.x; i < D * D; i += 256) { float wt = Wth[i]; sWd[i] = wt; sWs[i] = Wph[i] - wt; }
    for (int i = threadIdx.x; i < D * 64; i += 256) sW1[i] = W1[i];
    if (threadIdx.x < D) sbt[threadIdx.x] = bth[threadIdx.x] + bph[threadIdx.x];
    if (threadIdx.x >= 64 && threadIdx.x < 128) sb1[threadIdx.x - 64] = b1[threadIdx.x - 64];
    __syncthreads();
    int p = blockIdx.x * 256 + threadIdx.x;
    if (p >= E) return;
    int s = ssrc[p], d2 = sdst[p];
    float hs[D], hd[D], he[D];
    const float4* ps = (const float4*)(h + (size_t)s * D);
    const float4* pd = (const float4*)(h + (size_t)d2 * D);
    #pragma unroll
    for (int i = 0; i < D / 4; ++i) {
        float4 v = ps[i]; hs[4*i] = v.x; hs[4*i+1] = v.y; hs[4*i+2] = v.z; hs[4*i+3] = v.w;
        float4 w = pd[i]; hd[4*i] = w.x; hd[4*i+1] = w.y; hd[4*i+2] = w.z; hd[4*i+3] = w.w;
    }
    #pragma unroll
    for (int o = 0; o < D; ++o) he[o] = sbt[o];
    #pragma unroll
    for (int i = 0; i < D; ++i) {
        float a_ = hd[i], b_ = hs[i];
        #pragma unroll
        for (int o = 0; o < D; ++o) he[o] += a_ * sWd[i * D + o] + b_ * sWs[i * D + o];
    }
    #pragma unroll
    for (int o = 0; o < D; ++o) he[o] = fmaxf(he[o], 0.f);

    u32* grow = (u32*)g + (size_t)p * 32;
    for (int k0 = 0; k0 < 64; k0 += 8) {       // runtime loop: keeps code small
        float acc[8];
        #pragma unroll
        for (int j = 0; j < 8; ++j) acc[j] = sb1[k0 + j];
        #pragma unroll
        for (int o = 0; o < D; ++o) {
            float hv = he[o];
            #pragma unroll
            for (int j = 0; j < 8; ++j) acc[j] += hv * sW1[o * 64 + k0 + j];
        }
        u32 parts[4];
        #pragma unroll
        for (int j = 0; j < 4; ++j)
            parts[j] = (u32)f2b(fmaxf(acc[2*j], 0.f)) | ((u32)f2b(fmaxf(acc[2*j+1], 0.f)) << 16);
        *(uint4*)(grow + k0 / 2) = make_uint4(parts[0], parts[1], parts[2], parts[3]);
    }
}

// M[n][ko] (bf16) = sum_i h[n][i] * W2[k*1024 + i*32 + o]; slice 8 computes B[n][o] = sum_i h[n][i]*b2[i*32+o]
__global__ __launch_bounds__(256)
void k_MB(const float* __restrict__ h, fp W2, fp b2, u16* __restrict__ M,
          float* __restrict__ B, int N) {
    __shared__ float sh[128 * D];
    __shared__ float sb2[1024];
    int nblk = blockIdx.x / 9, slice = blockIdx.x % 9;
    int n0 = nblk * 128;
    int nn = min(128, N - n0);
    for (int i = threadIdx.x; i < nn * (D / 4); i += 256)
        ((float4*)sh)[i] = ((const float4*)(h + (size_t)n0 * D))[i];
    if (slice == 8)
        for (int i = threadIdx.x; i < 1024; i += 256) sb2[i] = b2[i];
    __syncthreads();
    if (slice < 8) {
        int ko = (slice << 8) + threadIdx.x;
        int k = ko >> 5, o = ko & 31;
        float w[D];
        const float* wp = W2 + (size_t)k * 1024 + o;
        #pragma unroll
        for (int i = 0; i < D; ++i) w[i] = wp[i * 32];
        for (int n = 0; n < nn; ++n) {
            const float4* hv = (const float4*)(sh + n * D);
            float acc = 0.f;
            #pragma unroll
            for (int i4 = 0; i4 < D / 4; ++i4) {
                float4 v = hv[i4];
                acc += v.x * w[4*i4] + v.y * w[4*i4+1] + v.z * w[4*i4+2] + v.w * w[4*i4+3];
            }
            M[(size_t)(n0 + n) * 2048 + ko] = f2b(acc);
        }
    } else {
        int o = threadIdx.x & 31, ng = threadIdx.x >> 5;
        for (int n = ng; n < nn; n += 8) {
            float acc = 0.f;
            #pragma unroll
            for (int i = 0; i < D; ++i) acc += sh[n * D + i] * sb2[i * 32 + o];
            B[(size_t)(n0 + n) * D + o] = acc;
        }
    }
}

// block per src node s: load M[s] row to LDS, apply to all out-edges, atomicAdd to a[dst]
__global__ void k_msg(const u16* __restrict__ M, const float* __restrict__ B,
                      const u16* __restrict__ g, const int* __restrict__ roff,
                      const int* __restrict__ sdst, float* __restrict__ a) {
    int s = blockIdx.x;
    int beg = roff[s], end = roff[s + 1];
    if (beg >= end) return;
    __shared__ float sM[2048];
    __shared__ float sB[D];
    __shared__ float sg[8][64];
    {
        uint4 pk = ((const uint4*)(M + (size_t)s * 2048))[threadIdx.x];
        int b0 = threadIdx.x * 8;
        sM[b0 + 0] = b2f(pk.x & 0xffff); sM[b0 + 1] = b2f(pk.x >> 16);
        sM[b0 + 2] = b2f(pk.y & 0xffff); sM[b0 + 3] = b2f(pk.y >> 16);
        sM[b0 + 4] = b2f(pk.z & 0xffff); sM[b0 + 5] = b2f(pk.z >> 16);
        sM[b0 + 6] = b2f(pk.w & 0xffff); sM[b0 + 7] = b2f(pk.w >> 16);
    }
    if (threadIdx.x < D) sB[threadIdx.x] = B[(size_t)s * D + threadIdx.x];
    __syncthreads();
    int sub = threadIdx.x >> 5, o = threadIdx.x & 31;
    for (int eb = beg; eb < end; eb += 8) {
        int nE = min(8, end - eb);
        if (sub < nE) {
            u32 pk = ((const u32*)g)[(size_t)(eb + sub) * 32 + o];
            sg[sub][2 * o] = b2f(pk & 0xffff);
            sg[sub][2 * o + 1] = b2f(pk >> 16);
        }
        __syncthreads();
        if (sub < nE) {
            float acc = sB[o];
            #pragma unroll
            for (int kk = 0; kk < 64; ++kk) acc += sg[sub][kk] * sM[kk * 32 + o];
            atomicAdd(&a[(size_t)sdst[eb + sub] * D + o], acc);
        }
        __syncthreads();
    }
}

// torch GRUCell; zeroes a in place for the next step
__global__ void k_gru(float* __restrict__ a, const float* __restrict__ h,
                      fp W_ih, fp b_ih, fp W_hh, fp b_hh,
                      float* __restrict__ hout, int N) {
    __shared__ float sa[8][D], sh[8][D];
    int n0 = blockIdx.x * 8;
    for (int i = threadIdx.x; i < 8 * D; i += 256) {
        int n = n0 + (i >> 5);
        if (n < N) {
            size_t idx = (size_t)n * D + (i & 31);
            sa[i >> 5][i & 31] = a[idx];
            sh[i >> 5][i & 31] = h[idx];
            a[idx] = 0.f;
        }
    }
    __syncthreads();
    int sub = threadIdx.x >> 5, o = threadIdx.x & 31;
    int n = n0 + sub;
    if (n >= N) return;
    float ir = b_ih[o], iz = b_ih[D + o], in_ = b_ih[2 * D + o];
    float hr = b_hh[o], hz = b_hh[D + o], hn = b_hh[2 * D + o];
    #pragma unroll
    for (int i = 0; i < D; ++i) {
        float av = sa[sub][i], hv = sh[sub][i];
        ir += av * W_ih[i * 96 + o];
        iz += av * W_ih[i * 96 + D + o];
        in_ += av * W_ih[i * 96 + 2 * D + o];
        hr += hv * W_hh[i * 96 + o];
        hz += hv * W_hh[i * 96 + D + o];
        hn += hv * W_hh[i * 96 + 2 * D + o];
    }
    float r = 1.f / (1.f + __expf(-(ir + hr)));
    float z = 1.f / (1.f + __expf(-(iz + hz)));
    float nn = tanhf(in_ + r * hn);
    hout[(size_t)n * D + o] = (1.f - z) * nn + z * sh[sub][o];
}

extern "C" void kernel_launch(void* const* d_in, const int* in_sizes, int n_in,
                              void* d_out, int out_size, void* d_ws, size_t ws_size,
                              hipStream_t stream) {
    fp x      = (fp)d_in[0];
    const int* src = (const int*)d_in[1];
    const int* dst = (const int*)d_in[2];
    fp W_emb  = (fp)d_in[3];
    fp b_emb  = (fp)d_in[4];
    fp W_th   = (fp)d_in[5];
    fp b_th   = (fp)d_in[6];
    fp W_ph   = (fp)d_in[7];
    fp b_ph   = (fp)d_in[8];
    fp W1     = (fp)d_in[9];
    fp b1     = (fp)d_in[10];
    fp W2     = (fp)d_in[11];
    fp b2     = (fp)d_in[12];
    fp W_ih   = (fp)d_in[13];
    fp b_ih   = (fp)d_in[14];
    fp W_hh   = (fp)d_in[15];
    fp b_hh   = (fp)d_in[16];

    const int N = in_sizes[0] / 2;   // x is [N,2]
    const int E = in_sizes[1];
    const int Npad = N + 4 - (N % 4);

    float* a      = (float*)d_ws;                       // N*D f32
    int*   cnt    = (int*)(a + (size_t)N * D);          // Npad
    int*   cursor = cnt + Npad;                         // N
    int*   roff   = cursor + N;                         // Npad (N+1 used)
    int*   ssrc   = roff + Npad;                        // E
    int*   sdst   = ssrc + E;                           // E
    float* hA     = (float*)(sdst + E);                 // N*D
    float* hB     = hA + (size_t)N * D;                 // N*D
    u16*   g      = (u16*)(hB + (size_t)N * D);         // E*64 bf16
    u16*   M      = g + (size_t)E * 64;                 // N*2048 bf16
    float* B      = (float*)(M + (size_t)N * 2048);     // N*D

    // zero a + cnt + cursor in one memset (contiguous)
    size_t zbytes = (char*)(cursor + N) - (char*)a;
    hipMemsetAsync(a, 0, zbytes, stream);

    int ndBlocks = (N * D + 255) / 256;
    int eBlocks  = (E + 255) / 256;

    k_embed<<<ndBlocks, 256, 0, stream>>>(x, W_emb, b_emb, hA, N);
    k_count<<<eBlocks, 256, 0, stream>>>(src, cnt, E);
    k_scan<<<1, 1024, 0, stream>>>(cnt, roff, N);
    k_scatter<<<eBlocks, 256, 0, stream>>>(src, dst, roff, cursor, ssrc, sdst, E);
    k_edge<<<eBlocks, 256, 0, stream>>>(hA, ssrc, sdst, W_th, b_th, W_ph, b_ph, W1, b1, g, E);

    int mBlocks = ((N + 127) / 128) * 9;
    float* hc = hA;
    float* hn_ = hB;
    for (int step = 0; step < 3; ++step) {
        k_MB<<<mBlocks, 256, 0, stream>>>(hc, W2, b2, M, B, N);
        k_msg<<<N, 256, 0, stream>>>(M, B, g, roff, sdst, a);
        float* dstbuf = (step == 2) ? (float*)d_out : hn_;
        k_gru<<<(N + 7) / 8, 256, 0, stream>>>(a, hc, W_ih, b_ih, W_hh, b_hh, dstbuf, N);
        float* t = hc; hc = hn_; hn_ = t;
    }
}

// Round 5
// 367.806 us; speedup vs baseline: 2.6780x; 1.0376x over previous
//
#include <hip/hip_runtime.h>
#include <hip/hip_bf16.h>

#define D 32

typedef const float* fp;
typedef unsigned short u16;
typedef unsigned int u32;

__device__ __forceinline__ float b2f(u32 lo16) { return __uint_as_float(lo16 << 16); }
__device__ __forceinline__ u16 f2b(float f) {
    u32 x = __float_as_uint(f);
    return (u16)((x + 0x7fffu + ((x >> 16) & 1u)) >> 16);   // RNE
}

// Precompose tiny weights: P = [A_u(2x32), c_u(32), A_v(2x32), c_v(32)]
// u[n] = x_n @ (W_emb@Wth) + (b_emb@Wth + bth + bph)
// v[n] = x_n @ (W_emb@(Wph-Wth)) + (b_emb@(Wph-Wth))
__global__ void k_prep(fp W_emb, fp b_emb, fp Wth, fp bth, fp Wph, fp bph,
                       float* __restrict__ P) {
    int o = threadIdx.x;
    if (o >= 32) return;
    float au0 = 0.f, au1 = 0.f, cu = 0.f, av0 = 0.f, av1 = 0.f, cv = 0.f;
    for (int i = 0; i < D; ++i) {
        float wt = Wth[i * D + o];
        float wd = Wph[i * D + o] - wt;
        au0 += W_emb[i] * wt;        // W_emb[0][i]
        au1 += W_emb[D + i] * wt;    // W_emb[1][i]
        cu  += b_emb[i] * wt;
        av0 += W_emb[i] * wd;
        av1 += W_emb[D + i] * wd;
        cv  += b_emb[i] * wd;
    }
    P[o]       = au0;
    P[32 + o]  = au1;
    P[64 + o]  = cu + bth[o] + bph[o];
    P[96 + o]  = av0;
    P[128 + o] = av1;
    P[160 + o] = cv;
}

// h, u, v directly from x (2 FLOPs per output)
__global__ void k_hev(fp x, fp W_emb, fp b_emb, const float* __restrict__ P,
                      float* __restrict__ h, float* __restrict__ u,
                      float* __restrict__ v, int N) {
    int t = blockIdx.x * 256 + threadIdx.x;
    if (t >= N * D) return;
    int n = t >> 5, o = t & 31;
    float x0 = x[2 * n], x1 = x[2 * n + 1];
    h[t] = x0 * W_emb[o] + x1 * W_emb[D + o] + b_emb[o];
    u[t] = x0 * P[o] + x1 * P[32 + o] + P[64 + o];
    v[t] = x0 * P[96 + o] + x1 * P[128 + o] + P[160 + o];
}

__global__ void k_count(const int* __restrict__ src, int* __restrict__ cnt, int E) {
    int e = blockIdx.x * 256 + threadIdx.x;
    if (e < E) atomicAdd(&cnt[src[e]], 1);
}

__global__ void k_scan(const int* __restrict__ cnt, int* __restrict__ roff, int N) {
    __shared__ int part[1024];
    int t = threadIdx.x;
    int per = (N + 1023) / 1024;
    int begin = t * per, end = min(begin + per, N);
    int s = 0;
    for (int i = begin; i < end; ++i) s += cnt[i];
    part[t] = s;
    __syncthreads();
    for (int off = 1; off < 1024; off <<= 1) {
        int v = (t >= off) ? part[t - off] : 0;
        __syncthreads();
        part[t] += v;
        __syncthreads();
    }
    int pre = (t == 0) ? 0 : part[t - 1];
    for (int i = begin; i < end; ++i) { roff[i] = pre; pre += cnt[i]; }
    if (t == 0) roff[N] = part[1023];
}

__global__ void k_scatter(const int* __restrict__ src, const int* __restrict__ dst,
                          const int* __restrict__ roff, int* __restrict__ cursor,
                          int* __restrict__ ssrc, int* __restrict__ sdst, int E) {
    int e = blockIdx.x * 256 + threadIdx.x;
    if (e >= E) return;
    int s = src[e];
    int p = roff[s] + atomicAdd(&cursor[s], 1);
    ssrc[p] = s;
    sdst[p] = dst[e];
}

// cooperative: 8 edges/block; lane o owns g[k=2o,2o+1]; he staged in LDS
__global__ __launch_bounds__(256)
void k_edge2(const float* __restrict__ u, const float* __restrict__ v,
             const int* __restrict__ ssrc, const int* __restrict__ sdst,
             fp W1, fp b1, u16* __restrict__ g, int E) {
    __shared__ float sW1[D * 64];
    __shared__ float sb1[64];
    __shared__ float she[8][D];
    for (int i = threadIdx.x; i < D * 64; i += 256) sW1[i] = W1[i];
    if (threadIdx.x < 64) sb1[threadIdx.x] = b1[threadIdx.x];
    __syncthreads();
    int sub = threadIdx.x >> 5, o = threadIdx.x & 31;
    const float2* w2p = (const float2*)sW1;
    for (int e0 = blockIdx.x * 8; e0 < E; e0 += gridDim.x * 8) {
        int e = e0 + sub;
        if (e < E) {
            int s = ssrc[e], d2 = sdst[e];
            she[sub][o] = fmaxf(u[(size_t)d2 * D + o] + v[(size_t)s * D + o], 0.f);
        }
        __syncthreads();
        if (e < E) {
            float a0 = sb1[2 * o], a1 = sb1[2 * o + 1];
            #pragma unroll
            for (int i = 0; i < D; ++i) {
                float hv = she[sub][i];
                float2 w = w2p[i * 32 + o];    // W1[i][2o], W1[i][2o+1]
                a0 += hv * w.x;
                a1 += hv * w.y;
            }
            ((u32*)g)[(size_t)e * 32 + o] =
                (u32)f2b(fmaxf(a0, 0.f)) | ((u32)f2b(fmaxf(a1, 0.f)) << 16);
        }
        __syncthreads();
    }
}

// M[n][ko] (bf16) = sum_i h[n][i]*W2[k*1024+i*32+o]; slice 8: B[n][o] = sum_i h[n][i]*b2[i*32+o]
__global__ __launch_bounds__(256)
void k_MB(const float* __restrict__ h, fp W2, fp b2, u16* __restrict__ M,
          float* __restrict__ B, int N) {
    __shared__ float sh[128 * D];
    __shared__ float sb2[1024];
    int nblk = blockIdx.x / 9, slice = blockIdx.x % 9;
    int n0 = nblk * 128;
    int nn = min(128, N - n0);
    for (int i = threadIdx.x; i < nn * (D / 4); i += 256)
        ((float4*)sh)[i] = ((const float4*)(h + (size_t)n0 * D))[i];
    if (slice == 8)
        for (int i = threadIdx.x; i < 1024; i += 256) sb2[i] = b2[i];
    __syncthreads();
    if (slice < 8) {
        int ko = (slice << 8) + threadIdx.x;
        int k = ko >> 5, o = ko & 31;
        float w[D];
        const float* wp = W2 + (size_t)k * 1024 + o;
        #pragma unroll
        for (int i = 0; i < D; ++i) w[i] = wp[i * 32];
        for (int n = 0; n < nn; ++n) {
            const float4* hv = (const float4*)(sh + n * D);
            float acc = 0.f;
            #pragma unroll
            for (int i4 = 0; i4 < D / 4; ++i4) {
                float4 vv = hv[i4];
                acc += vv.x * w[4*i4] + vv.y * w[4*i4+1] + vv.z * w[4*i4+2] + vv.w * w[4*i4+3];
            }
            M[(size_t)(n0 + n) * 2048 + ko] = f2b(acc);
        }
    } else {
        int o = threadIdx.x & 31, ng = threadIdx.x >> 5;
        for (int n = ng; n < nn; n += 8) {
            float acc = 0.f;
            #pragma unroll
            for (int i = 0; i < D; ++i) acc += sh[n * D + i] * sb2[i * 32 + o];
            B[(size_t)(n0 + n) * D + o] = acc;
        }
    }
}

// block per src node s: M[s] row to LDS, apply to all out-edges, atomicAdd to a[dst]
__global__ void k_msg(const u16* __restrict__ M, const float* __restrict__ B,
                      const u16* __restrict__ g, const int* __restrict__ roff,
                      const int* __restrict__ sdst, float* __restrict__ a) {
    int s = blockIdx.x;
    int beg = roff[s], end = roff[s + 1];
    if (beg >= end) return;
    __shared__ float sM[2048];
    __shared__ float sB[D];
    __shared__ float sg[8][64];
    {
        uint4 pk = ((const uint4*)(M + (size_t)s * 2048))[threadIdx.x];
        int b0 = threadIdx.x * 8;
        sM[b0 + 0] = b2f(pk.x & 0xffff); sM[b0 + 1] = b2f(pk.x >> 16);
        sM[b0 + 2] = b2f(pk.y & 0xffff); sM[b0 + 3] = b2f(pk.y >> 16);
        sM[b0 + 4] = b2f(pk.z & 0xffff); sM[b0 + 5] = b2f(pk.z >> 16);
        sM[b0 + 6] = b2f(pk.w & 0xffff); sM[b0 + 7] = b2f(pk.w >> 16);
    }
    if (threadIdx.x < D) sB[threadIdx.x] = B[(size_t)s * D + threadIdx.x];
    __syncthreads();
    int sub = threadIdx.x >> 5, o = threadIdx.x & 31;
    for (int eb = beg; eb < end; eb += 8) {
        int nE = min(8, end - eb);
        if (sub < nE) {
            u32 pk = ((const u32*)g)[(size_t)(eb + sub) * 32 + o];
            sg[sub][2 * o] = b2f(pk & 0xffff);
            sg[sub][2 * o + 1] = b2f(pk >> 16);
        }
        __syncthreads();
        if (sub < nE) {
            float acc = sB[o];
            #pragma unroll
            for (int kk = 0; kk < 64; ++kk) acc += sg[sub][kk] * sM[kk * 32 + o];
            atomicAdd(&a[(size_t)sdst[eb + sub] * D + o], acc);
        }
        __syncthreads();
    }
}

// torch GRUCell, weights in LDS; zeroes a in place for the next step
__global__ __launch_bounds__(256)
void k_gru(float* __restrict__ a, const float* __restrict__ h,
           fp W_ih, fp b_ih, fp W_hh, fp b_hh,
           float* __restrict__ hout, int N) {
    __shared__ float sWi[D * 96], sWh[D * 96], sbi[96], sbh[96];
    __shared__ float sa[8][D], sh[8][D];
    for (int i = threadIdx.x; i < D * 96; i += 256) { sWi[i] = W_ih[i]; sWh[i] = W_hh[i]; }
    if (threadIdx.x < 96) { sbi[threadIdx.x] = b_ih[threadIdx.x]; sbh[threadIdx.x] = b_hh[threadIdx.x]; }
    int n0 = blockIdx.x * 8;
    for (int i = threadIdx.x; i < 8 * D; i += 256) {
        int n = n0 + (i >> 5);
        if (n < N) {
            size_t idx = (size_t)n * D + (i & 31);
            sa[i >> 5][i & 31] = a[idx];
            sh[i >> 5][i & 31] = h[idx];
            a[idx] = 0.f;
        }
    }
    __syncthreads();
    int sub = threadIdx.x >> 5, o = threadIdx.x & 31;
    int n = n0 + sub;
    if (n >= N) return;
    float ir = sbi[o], iz = sbi[D + o], in_ = sbi[2 * D + o];
    float hr = sbh[o], hz = sbh[D + o], hn = sbh[2 * D + o];
    #pragma unroll
    for (int i = 0; i < D; ++i) {
        float av = sa[sub][i], hv = sh[sub][i];
        ir += av * sWi[i * 96 + o];
        iz += av * sWi[i * 96 + D + o];
        in_ += av * sWi[i * 96 + 2 * D + o];
        hr += hv * sWh[i * 96 + o];
        hz += hv * sWh[i * 96 + D + o];
        hn += hv * sWh[i * 96 + 2 * D + o];
    }
    float r = 1.f / (1.f + __expf(-(ir + hr)));
    float z = 1.f / (1.f + __expf(-(iz + hz)));
    float nn = tanhf(in_ + r * hn);
    hout[(size_t)n * D + o] = (1.f - z) * nn + z * sh[sub][o];
}

extern "C" void kernel_launch(void* const* d_in, const int* in_sizes, int n_in,
                              void* d_out, int out_size, void* d_ws, size_t ws_size,
                              hipStream_t stream) {
    fp x      = (fp)d_in[0];
    const int* src = (const int*)d_in[1];
    const int* dst = (const int*)d_in[2];
    fp W_emb  = (fp)d_in[3];
    fp b_emb  = (fp)d_in[4];
    fp W_th   = (fp)d_in[5];
    fp b_th   = (fp)d_in[6];
    fp W_ph   = (fp)d_in[7];
    fp b_ph   = (fp)d_in[8];
    fp W1     = (fp)d_in[9];
    fp b1     = (fp)d_in[10];
    fp W2     = (fp)d_in[11];
    fp b2     = (fp)d_in[12];
    fp W_ih   = (fp)d_in[13];
    fp b_ih   = (fp)d_in[14];
    fp W_hh   = (fp)d_in[15];
    fp b_hh   = (fp)d_in[16];

    const int N = in_sizes[0] / 2;
    const int E = in_sizes[1];
    const int Npad = N + 4 - (N % 4);

    float* a      = (float*)d_ws;                       // N*D f32
    int*   cnt    = (int*)(a + (size_t)N * D);          // Npad
    int*   cursor = cnt + Npad;                         // N
    int*   roff   = cursor + N;                         // Npad (N+1 used)
    int*   ssrc   = roff + Npad;                        // E
    int*   sdst   = ssrc + E;                           // E
    float* hA     = (float*)(sdst + E);                 // N*D
    float* hB     = hA + (size_t)N * D;                 // N*D
    u16*   g      = (u16*)(hB + (size_t)N * D);         // E*64 bf16
    u16*   M      = g + (size_t)E * 64;                 // N*2048 bf16
    float* B      = (float*)(M + (size_t)N * 2048);     // N*D
    float* P      = B + (size_t)N * D;                  // 192
    float* u      = P + 256;                            // N*D
    float* v      = u + (size_t)N * D;                  // N*D

    size_t zbytes = (char*)(cursor + N) - (char*)a;
    hipMemsetAsync(a, 0, zbytes, stream);

    int ndBlocks = (N * D + 255) / 256;
    int eBlocks  = (E + 255) / 256;

    k_prep<<<1, 64, 0, stream>>>(W_emb, b_emb, W_th, b_th, W_ph, b_ph, P);
    k_hev<<<ndBlocks, 256, 0, stream>>>(x, W_emb, b_emb, P, hA, u, v, N);
    k_count<<<eBlocks, 256, 0, stream>>>(src, cnt, E);
    k_scan<<<1, 1024, 0, stream>>>(cnt, roff, N);
    k_scatter<<<eBlocks, 256, 0, stream>>>(src, dst, roff, cursor, ssrc, sdst, E);
    k_edge2<<<2048, 256, 0, stream>>>(u, v, ssrc, sdst, W1, b1, g, E);

    int mBlocks = ((N + 127) / 128) * 9;
    float* hc = hA;
    float* hn_ = hB;
    for (int step = 0; step < 3; ++step) {
        k_MB<<<mBlocks, 256, 0, stream>>>(hc, W2, b2, M, B, N);
        k_msg<<<N, 256, 0, stream>>>(M, B, g, roff, sdst, a);
        float* dstbuf = (step == 2) ? (float*)d_out : hn_;
        k_gru<<<(N + 7) / 8, 256, 0, stream>>>(a, hc, W_ih, b_ih, W_hh, b_hh, dstbuf, N);
        float* t = hc; hc = hn_; hn_ = t;
    }
}

// Round 6
// 298.473 us; speedup vs baseline: 3.3001x; 1.2323x over previous
//
#include <hip/hip_runtime.h>
#include <hip/hip_bf16.h>

#define D 32

typedef const float* fp;
typedef unsigned short u16;
typedef unsigned int u32;

using short8 = __attribute__((ext_vector_type(8))) short;
using f32x4  = __attribute__((ext_vector_type(4))) float;

__device__ __forceinline__ float b2f(u32 lo16) { return __uint_as_float(lo16 << 16); }
__device__ __forceinline__ u16 f2b(float f) {
    u32 x = __float_as_uint(f);
    return (u16)((x + 0x7fffu + ((x >> 16) & 1u)) >> 16);   // RNE
}

// Precompose tiny weights: u[n] = x_n@(W_emb@Wth) + (b_emb@Wth + bth + bph); v analog with (Wph-Wth)
__global__ void k_prep(fp W_emb, fp b_emb, fp Wth, fp bth, fp Wph, fp bph,
                       float* __restrict__ P) {
    int o = threadIdx.x;
    if (o >= 32) return;
    float au0 = 0.f, au1 = 0.f, cu = 0.f, av0 = 0.f, av1 = 0.f, cv = 0.f;
    for (int i = 0; i < D; ++i) {
        float wt = Wth[i * D + o];
        float wd = Wph[i * D + o] - wt;
        au0 += W_emb[i] * wt;
        au1 += W_emb[D + i] * wt;
        cu  += b_emb[i] * wt;
        av0 += W_emb[i] * wd;
        av1 += W_emb[D + i] * wd;
        cv  += b_emb[i] * wd;
    }
    P[o]       = au0;
    P[32 + o]  = au1;
    P[64 + o]  = cu + bth[o] + bph[o];
    P[96 + o]  = av0;
    P[128 + o] = av1;
    P[160 + o] = cv;
}

// W2 -> MFMA-B-fragment layout: W2f[T*512 + l*8 + j] = bf16(W2e[i=(l>>4)*8+j][ko=T*16+(l&15)])
__global__ void k_w2frag(fp W2, u16* __restrict__ W2f) {
    int idx = blockIdx.x * 256 + threadIdx.x;   // 65536 total
    int T = idx >> 9, r = idx & 511, l = r >> 3, j = r & 7;
    int ko = T * 16 + (l & 15);
    int i = (l >> 4) * 8 + j;
    W2f[idx] = f2b(W2[(size_t)(ko >> 5) * 1024 + i * 32 + (ko & 31)]);
}

// h (f32 + bf16), u, v directly from x
__global__ void k_hev(fp x, fp W_emb, fp b_emb, const float* __restrict__ P,
                      float* __restrict__ h, u16* __restrict__ hbf,
                      float* __restrict__ u, float* __restrict__ v, int N) {
    int t = blockIdx.x * 256 + threadIdx.x;
    if (t >= N * D) return;
    int n = t >> 5, o = t & 31;
    float x0 = x[2 * n], x1 = x[2 * n + 1];
    float hv = x0 * W_emb[o] + x1 * W_emb[D + o] + b_emb[o];
    h[t] = hv;
    hbf[t] = f2b(hv);
    u[t] = x0 * P[o] + x1 * P[32 + o] + P[64 + o];
    v[t] = x0 * P[96 + o] + x1 * P[128 + o] + P[160 + o];
}

__global__ void k_count(const int* __restrict__ src, int* __restrict__ cnt, int E) {
    int e = blockIdx.x * 256 + threadIdx.x;
    if (e < E) atomicAdd(&cnt[src[e]], 1);
}

__global__ void k_scan(const int* __restrict__ cnt, int* __restrict__ roff, int N) {
    __shared__ int part[1024];
    int t = threadIdx.x;
    int per = (N + 1023) / 1024;
    int begin = t * per, end = min(begin + per, N);
    int s = 0;
    for (int i = begin; i < end; ++i) s += cnt[i];
    part[t] = s;
    __syncthreads();
    for (int off = 1; off < 1024; off <<= 1) {
        int v = (t >= off) ? part[t - off] : 0;
        __syncthreads();
        part[t] += v;
        __syncthreads();
    }
    int pre = (t == 0) ? 0 : part[t - 1];
    for (int i = begin; i < end; ++i) { roff[i] = pre; pre += cnt[i]; }
    if (t == 0) roff[N] = part[1023];
}

__global__ void k_scatter(const int* __restrict__ src, const int* __restrict__ dst,
                          const int* __restrict__ roff, int* __restrict__ cursor,
                          int* __restrict__ ssrc, int* __restrict__ sdst, int E) {
    int e = blockIdx.x * 256 + threadIdx.x;
    if (e >= E) return;
    int s = src[e];
    int p = roff[s] + atomicAdd(&cursor[s], 1);
    ssrc[p] = s;
    sdst[p] = dst[e];
}

// cooperative: 8 edges/block; lane o owns g[k=2o,2o+1]; he staged in LDS
__global__ __launch_bounds__(256)
void k_edge2(const float* __restrict__ u, const float* __restrict__ v,
             const int* __restrict__ ssrc, const int* __restrict__ sdst,
             fp W1, fp b1, u16* __restrict__ g, int E) {
    __shared__ float sW1[D * 64];
    __shared__ float sb1[64];
    __shared__ float she[8][D];
    for (int i = threadIdx.x; i < D * 64; i += 256) sW1[i] = W1[i];
    if (threadIdx.x < 64) sb1[threadIdx.x] = b1[threadIdx.x];
    __syncthreads();
    int sub = threadIdx.x >> 5, o = threadIdx.x & 31;
    const float2* w2p = (const float2*)sW1;
    for (int e0 = blockIdx.x * 8; e0 < E; e0 += gridDim.x * 8) {
        int e = e0 + sub;
        if (e < E) {
            int s = ssrc[e], d2 = sdst[e];
            she[sub][o] = fmaxf(u[(size_t)d2 * D + o] + v[(size_t)s * D + o], 0.f);
        }
        __syncthreads();
        if (e < E) {
            float a0 = sb1[2 * o], a1 = sb1[2 * o + 1];
            #pragma unroll
            for (int i = 0; i < D; ++i) {
                float hv = she[sub][i];
                float2 w = w2p[i * 32 + o];
                a0 += hv * w.x;
                a1 += hv * w.y;
            }
            ((u32*)g)[(size_t)e * 32 + o] =
                (u32)f2b(fmaxf(a0, 0.f)) | ((u32)f2b(fmaxf(a1, 0.f)) << 16);
        }
        __syncthreads();
    }
}

// MFMA M-GEMM: block = 16 n x 256 ko; 4 waves x 4 mfma_f32_16x16x32_bf16
__global__ __launch_bounds__(256)
void k_Mm(const u16* __restrict__ hbf, const u16* __restrict__ W2f,
          u16* __restrict__ M, int N) {
    __shared__ u16 sM[16][264];
    int n0 = (blockIdx.x >> 3) * 16;
    if (n0 >= N) return;
    int koBase = (blockIdx.x & 7) * 256;
    int w = threadIdx.x >> 6, l = threadIdx.x & 63;
    int arow = n0 + (l & 15);
    if (arow >= N) arow = N - 1;   // tail-safe (N%16==0 in practice)
    short8 a = *(const short8*)(hbf + (size_t)arow * 32 + (l >> 4) * 8);
    int T0 = (koBase >> 4) + w * 4;
    const u16* bp = W2f + (size_t)T0 * 512 + l * 8;
    short8 b0 = *(const short8*)(bp);
    short8 b1 = *(const short8*)(bp + 512);
    short8 b2v = *(const short8*)(bp + 1024);
    short8 b3 = *(const short8*)(bp + 1536);
    f32x4 acc0{0.f,0.f,0.f,0.f}, acc1{0.f,0.f,0.f,0.f}, acc2{0.f,0.f,0.f,0.f}, acc3{0.f,0.f,0.f,0.f};
    acc0 = __builtin_amdgcn_mfma_f32_16x16x32_bf16(a, b0, acc0, 0, 0, 0);
    acc1 = __builtin_amdgcn_mfma_f32_16x16x32_bf16(a, b1, acc1, 0, 0, 0);
    acc2 = __builtin_amdgcn_mfma_f32_16x16x32_bf16(a, b2v, acc2, 0, 0, 0);
    acc3 = __builtin_amdgcn_mfma_f32_16x16x32_bf16(a, b3, acc3, 0, 0, 0);
    int rbase = (l >> 4) * 4, col = l & 15;
    #pragma unroll
    for (int r = 0; r < 4; ++r) {
        sM[rbase + r][w * 64 +  0 + col] = f2b(acc0[r]);
        sM[rbase + r][w * 64 + 16 + col] = f2b(acc1[r]);
        sM[rbase + r][w * 64 + 32 + col] = f2b(acc2[r]);
        sM[rbase + r][w * 64 + 48 + col] = f2b(acc3[r]);
    }
    __syncthreads();
    int i = threadIdx.x >> 4, seg = threadIdx.x & 15;
    if (n0 + i < N) {
        const uint4* srcp = (const uint4*)(&sM[i][seg * 16]);
        uint4* dstp = (uint4*)(M + (size_t)(n0 + i) * 2048 + koBase + seg * 16);
        dstp[0] = srcp[0];
        dstp[1] = srcp[1];
    }
}

// B[n][o] = sum_i h[n][i] * b2[i*32+o]
__global__ __launch_bounds__(256)
void k_B(const float* __restrict__ h, fp b2, float* __restrict__ B, int N) {
    __shared__ float sb2[1024];
    for (int i = threadIdx.x; i < 1024; i += 256) sb2[i] = b2[i];
    __syncthreads();
    int t = blockIdx.x * 256 + threadIdx.x;
    if (t >= N * D) return;
    int n = t >> 5, o = t & 31;
    const float4* hv = (const float4*)(h + (size_t)n * D);
    float acc = 0.f;
    #pragma unroll
    for (int i4 = 0; i4 < 8; ++i4) {
        float4 v = hv[i4];
        acc += v.x * sb2[(4 * i4) * 32 + o] + v.y * sb2[(4 * i4 + 1) * 32 + o]
             + v.z * sb2[(4 * i4 + 2) * 32 + o] + v.w * sb2[(4 * i4 + 3) * 32 + o];
    }
    B[t] = acc;
}

// block per src node s: M[s] row to LDS, apply to all out-edges, atomicAdd to a[dst]
__global__ void k_msg(const u16* __restrict__ M, const float* __restrict__ B,
                      const u16* __restrict__ g, const int* __restrict__ roff,
                      const int* __restrict__ sdst, float* __restrict__ a) {
    int s = blockIdx.x;
    int beg = roff[s], end = roff[s + 1];
    if (beg >= end) return;
    __shared__ float sM[2048];
    __shared__ float sB[D];
    __shared__ float sg[8][64];
    {
        uint4 pk = ((const uint4*)(M + (size_t)s * 2048))[threadIdx.x];
        int b0 = threadIdx.x * 8;
        sM[b0 + 0] = b2f(pk.x & 0xffff); sM[b0 + 1] = b2f(pk.x >> 16);
        sM[b0 + 2] = b2f(pk.y & 0xffff); sM[b0 + 3] = b2f(pk.y >> 16);
        sM[b0 + 4] = b2f(pk.z & 0xffff); sM[b0 + 5] = b2f(pk.z >> 16);
        sM[b0 + 6] = b2f(pk.w & 0xffff); sM[b0 + 7] = b2f(pk.w >> 16);
    }
    if (threadIdx.x < D) sB[threadIdx.x] = B[(size_t)s * D + threadIdx.x];
    __syncthreads();
    int sub = threadIdx.x >> 5, o = threadIdx.x & 31;
    for (int eb = beg; eb < end; eb += 8) {
        int nE = min(8, end - eb);
        if (sub < nE) {
            u32 pk = ((const u32*)g)[(size_t)(eb + sub) * 32 + o];
            sg[sub][2 * o] = b2f(pk & 0xffff);
            sg[sub][2 * o + 1] = b2f(pk >> 16);
        }
        __syncthreads();
        if (sub < nE) {
            float acc = sB[o];
            #pragma unroll
            for (int kk = 0; kk < 64; ++kk) acc += sg[sub][kk] * sM[kk * 32 + o];
            atomicAdd(&a[(size_t)sdst[eb + sub] * D + o], acc);
        }
        __syncthreads();
    }
}

// torch GRUCell, weights in LDS; zeroes a in place; writes f32 + bf16 h
__global__ __launch_bounds__(256)
void k_gru(float* __restrict__ a, const float* __restrict__ h,
           fp W_ih, fp b_ih, fp W_hh, fp b_hh,
           float* __restrict__ hout, u16* __restrict__ hbf, int N) {
    __shared__ float sWi[D * 96], sWh[D * 96], sbi[96], sbh[96];
    __shared__ float sa[8][D], sh[8][D];
    for (int i = threadIdx.x; i < D * 96; i += 256) { sWi[i] = W_ih[i]; sWh[i] = W_hh[i]; }
    if (threadIdx.x < 96) { sbi[threadIdx.x] = b_ih[threadIdx.x]; sbh[threadIdx.x] = b_hh[threadIdx.x]; }
    int n0 = blockIdx.x * 8;
    for (int i = threadIdx.x; i < 8 * D; i += 256) {
        int n = n0 + (i >> 5);
        if (n < N) {
            size_t idx = (size_t)n * D + (i & 31);
            sa[i >> 5][i & 31] = a[idx];
            sh[i >> 5][i & 31] = h[idx];
            a[idx] = 0.f;
        }
    }
    __syncthreads();
    int sub = threadIdx.x >> 5, o = threadIdx.x & 31;
    int n = n0 + sub;
    if (n >= N) return;
    float ir = sbi[o], iz = sbi[D + o], in_ = sbi[2 * D + o];
    float hr = sbh[o], hz = sbh[D + o], hn = sbh[2 * D + o];
    #pragma unroll
    for (int i = 0; i < D; ++i) {
        float av = sa[sub][i], hv = sh[sub][i];
        ir += av * sWi[i * 96 + o];
        iz += av * sWi[i * 96 + D + o];
        in_ += av * sWi[i * 96 + 2 * D + o];
        hr += hv * sWh[i * 96 + o];
        hz += hv * sWh[i * 96 + D + o];
        hn += hv * sWh[i * 96 + 2 * D + o];
    }
    float r = 1.f / (1.f + __expf(-(ir + hr)));
    float z = 1.f / (1.f + __expf(-(iz + hz)));
    float nn = tanhf(in_ + r * hn);
    float hv2 = (1.f - z) * nn + z * sh[sub][o];
    size_t idx = (size_t)n * D + o;
    hout[idx] = hv2;
    hbf[idx] = f2b(hv2);
}

extern "C" void kernel_launch(void* const* d_in, const int* in_sizes, int n_in,
                              void* d_out, int out_size, void* d_ws, size_t ws_size,
                              hipStream_t stream) {
    fp x      = (fp)d_in[0];
    const int* src = (const int*)d_in[1];
    const int* dst = (const int*)d_in[2];
    fp W_emb  = (fp)d_in[3];
    fp b_emb  = (fp)d_in[4];
    fp W_th   = (fp)d_in[5];
    fp b_th   = (fp)d_in[6];
    fp W_ph   = (fp)d_in[7];
    fp b_ph   = (fp)d_in[8];
    fp W1     = (fp)d_in[9];
    fp b1     = (fp)d_in[10];
    fp W2     = (fp)d_in[11];
    fp b2     = (fp)d_in[12];
    fp W_ih   = (fp)d_in[13];
    fp b_ih   = (fp)d_in[14];
    fp W_hh   = (fp)d_in[15];
    fp b_hh   = (fp)d_in[16];

    const int N = in_sizes[0] / 2;
    const int E = in_sizes[1];
    const int Npad = N + 4 - (N % 4);

    float* a      = (float*)d_ws;                       // N*D f32
    int*   cnt    = (int*)(a + (size_t)N * D);          // Npad
    int*   cursor = cnt + Npad;                         // N
    int*   roff   = cursor + N;                         // Npad (N+1 used)
    int*   ssrc   = roff + Npad;                        // E
    int*   sdst   = ssrc + E;                           // E
    float* hA     = (float*)(sdst + E);                 // N*D
    float* hB     = hA + (size_t)N * D;                 // N*D
    u16*   g      = (u16*)(hB + (size_t)N * D);         // E*64 bf16
    u16*   M      = g + (size_t)E * 64;                 // N*2048 bf16
    float* B      = (float*)(M + (size_t)N * 2048);     // N*D
    float* P      = B + (size_t)N * D;                  // 256
    float* u      = P + 256;                            // N*D
    float* v      = u + (size_t)N * D;                  // N*D
    u16*   hbf    = (u16*)(v + (size_t)N * D);          // N*D bf16
    u16*   W2f    = hbf + (size_t)N * D;                // 65536 bf16

    size_t zbytes = (char*)(cursor + N) - (char*)a;
    hipMemsetAsync(a, 0, zbytes, stream);

    int ndBlocks = (N * D + 255) / 256;
    int eBlocks  = (E + 255) / 256;

    k_prep<<<1, 64, 0, stream>>>(W_emb, b_emb, W_th, b_th, W_ph, b_ph, P);
    k_w2frag<<<256, 256, 0, stream>>>(W2, W2f);
    k_hev<<<ndBlocks, 256, 0, stream>>>(x, W_emb, b_emb, P, hA, hbf, u, v, N);
    k_count<<<eBlocks, 256, 0, stream>>>(src, cnt, E);
    k_scan<<<1, 1024, 0, stream>>>(cnt, roff, N);
    k_scatter<<<eBlocks, 256, 0, stream>>>(src, dst, roff, cursor, ssrc, sdst, E);
    k_edge2<<<2048, 256, 0, stream>>>(u, v, ssrc, sdst, W1, b1, g, E);

    int mmBlocks = ((N + 15) / 16) * 8;
    float* hc = hA;
    float* hn_ = hB;
    for (int step = 0; step < 3; ++step) {
        k_Mm<<<mmBlocks, 256, 0, stream>>>(hbf, W2f, M, N);
        k_B<<<ndBlocks, 256, 0, stream>>>(hc, b2, B, N);
        k_msg<<<N, 256, 0, stream>>>(M, B, g, roff, sdst, a);
        float* dstbuf = (step == 2) ? (float*)d_out : hn_;
        k_gru<<<(N + 7) / 8, 256, 0, stream>>>(a, hc, W_ih, b_ih, W_hh, b_hh, dstbuf, hbf, N);
        float* t = hc; hc = hn_; hn_ = t;
    }
}